// Round 6
// baseline (542.040 us; speedup 1.0000x reference)
//
#include <hip/hip_runtime.h>
#include <cstdint>
#include <cstddef>

// Problem constants
#define BATCH 4
#define SEQ   2048
#define CMOD  1024
#define NH    16
#define DH    64
#define LOG100 4.6051701859880914f
#define LOG2E  1.4426950408889634f

typedef __attribute__((ext_vector_type(8))) short bf16x8;
typedef __attribute__((ext_vector_type(4))) float f32x4;
typedef __attribute__((ext_vector_type(16))) float f32x16;

__device__ __forceinline__ float bf2f(uint16_t u) {
    union { uint32_t i; float f; } x; x.i = ((uint32_t)u) << 16; return x.f;
}
__device__ __forceinline__ uint16_t f2bf(float f) {
    union { float f; uint32_t i; } x; x.f = f;
    uint32_t u = x.i;
    return (uint16_t)((u + 0x7FFFu + ((u >> 16) & 1u)) >> 16);  // RNE
}
__device__ __forceinline__ float exp2_fast(float x) {
    float r; asm("v_exp_f32 %0, %1" : "=v"(r) : "v"(x)); return r;
}
__device__ __forceinline__ uint32_t cvt_pk_bf16(float lo, float hi) {
    uint32_t r;
    asm("v_cvt_pk_bf16_f32 %0, %1, %2" : "=v"(r) : "v"(lo), "v"(hi));
    return r;
}
__device__ __forceinline__ void p32swap(uint32_t& x, uint32_t& y) {
#if __has_builtin(__builtin_amdgcn_permlane32_swap)
    auto r = __builtin_amdgcn_permlane32_swap(x, y, false, false);
    x = r[0]; y = r[1];
#else
    asm volatile("v_permlane32_swap_b32 %0, %1\n\ts_nop 1" : "+v"(x), "+v"(y));
#endif
}

__device__ __forceinline__ void gload_lds16(const void* g, void* l) {
    __builtin_amdgcn_global_load_lds(
        (const __attribute__((address_space(1))) uint32_t*)g,
        (__attribute__((address_space(3))) uint32_t*)l,
        16, 0, 0);
}

// ---------------- fp32 -> bf16 convert ----------------
__global__ __launch_bounds__(256) void cvt_kernel(const float* __restrict__ in,
                                                  uint16_t* __restrict__ out, int n) {
    int i = (blockIdx.x * 256 + threadIdx.x) * 4;
    if (i >= n) return;
    float4 f = *(const float4*)(in + i);
    ushort4 o;
    o.x = f2bf(f.x); o.y = f2bf(f.y); o.z = f2bf(f.z); o.w = f2bf(f.w);
    *(ushort4*)(out + i) = o;
}

// ---------------- bf16 GEMM, B-transposed input (m97 structure) ----------------
// C[M,N] = A[M,K] * B[N,K]^T ; 128x128 tile, BK=32, 4 waves, 4x4 16x16x32 frags/wave
// mode 0: QKV epilogue -> q normalized*scale_h*log2e (bf16 [B,H,L,D]),
//         k normalized (bf16 [B,H,L,D]), v+bias pre-transposed (bf16 [B,H,D,L])
// mode 1: proj epilogue -> fp32 out + b_proj
__global__ __launch_bounds__(256) void gemm_bt_kernel(
    const uint16_t* __restrict__ A, const uint16_t* __restrict__ B,
    int M, int N, int K, int mode,
    uint16_t* __restrict__ qb, uint16_t* __restrict__ kb, uint16_t* __restrict__ vtb,
    const float* __restrict__ q_bias, const float* __restrict__ v_bias,
    const float* __restrict__ scale_mul_log,
    float* __restrict__ outp, const float* __restrict__ b_proj)
{
    __shared__ __align__(16) uint16_t As[128 * 32];
    __shared__ __align__(16) uint16_t Bs[128 * 32];
    const int t = threadIdx.x;
    const int wave = t >> 6, lane = t & 63;
    const int g = lane >> 4, c16 = lane & 15;
    const int m0 = blockIdx.x * 128, n0 = blockIdx.y * 128;
    const int wm = (wave >> 1) * 64, wn = (wave & 1) * 64;

    f32x4 acc[4][4];
#pragma unroll
    for (int mt = 0; mt < 4; mt++)
#pragma unroll
        for (int nt = 0; nt < 4; nt++) acc[mt][nt] = (f32x4){0.f, 0.f, 0.f, 0.f};

    for (int k0 = 0; k0 < K; k0 += 32) {
        __syncthreads();
#pragma unroll
        for (int i = 0; i < 2; i++) {
            int cc = i * 256 + t;           // 512 chunks of 8 elems
            int row = cc >> 2, col = (cc & 3) * 8;
            gload_lds16(A + (size_t)(m0 + row) * K + k0 + col, &As[cc * 8]);
            gload_lds16(B + (size_t)(n0 + row) * K + k0 + col, &Bs[cc * 8]);
        }
        __syncthreads();
        bf16x8 af[4], bfv[4];
#pragma unroll
        for (int mt = 0; mt < 4; mt++)
            af[mt] = *(const bf16x8*)&As[(wm + mt * 16 + c16) * 32 + g * 8];
#pragma unroll
        for (int nt = 0; nt < 4; nt++)
            bfv[nt] = *(const bf16x8*)&Bs[(wn + nt * 16 + c16) * 32 + g * 8];
#pragma unroll
        for (int mt = 0; mt < 4; mt++)
#pragma unroll
            for (int nt = 0; nt < 4; nt++)
                acc[mt][nt] = __builtin_amdgcn_mfma_f32_16x16x32_bf16(af[mt], bfv[nt], acc[mt][nt], 0, 0, 0);
    }

    if (mode == 0) {
        const int colbase = n0 + wn;          // multiple of 64 -> single (tt, head) per wave
        const int tt = colbase >> 10;
        const int cc0 = colbase & 1023;
        const int hh = cc0 >> 6;
        float qmul = 1.0f;
        if (tt == 0) qmul = __expf(fminf(scale_mul_log[hh], LOG100)) * LOG2E;
#pragma unroll
        for (int mt = 0; mt < 4; mt++) {
            float vals[4][4];
            float n2[4] = {0.f, 0.f, 0.f, 0.f};
#pragma unroll
            for (int nt = 0; nt < 4; nt++) {
                const int ci = cc0 + nt * 16 + c16;   // 0..1023 within qkv third
                float badd = 0.f;
                if (tt == 0) badd = q_bias[ci];
                else if (tt == 2) badd = v_bias[ci];
#pragma unroll
                for (int r = 0; r < 4; r++) {
                    float v = acc[mt][nt][r] + badd;
                    vals[nt][r] = v;
                    n2[r] += v * v;
                }
            }
            float rs[4];
            if (tt < 2) {   // L2-normalize q (with scale*log2e) and k over the 64-wide head dim
#pragma unroll
                for (int r = 0; r < 4; r++) {
                    float s = n2[r];
                    s += __shfl_xor(s, 1, 64);
                    s += __shfl_xor(s, 2, 64);
                    s += __shfl_xor(s, 4, 64);
                    s += __shfl_xor(s, 8, 64);
                    rs[r] = qmul / fmaxf(sqrtf(s), 1e-12f);
                }
            } else {
#pragma unroll
                for (int r = 0; r < 4; r++) rs[r] = 1.0f;
            }
#pragma unroll
            for (int nt = 0; nt < 4; nt++) {
                const int dd = (cc0 + nt * 16 + c16) & 63;
#pragma unroll
                for (int r = 0; r < 4; r++) {
                    const int row = m0 + wm + mt * 16 + g * 4 + r;   // b*2048 + l
                    const int bb = row >> 11, ll = row & 2047;
                    const size_t bhx = (size_t)bb * NH + hh;
                    const uint16_t val = f2bf(vals[nt][r] * rs[r]);
                    if (tt == 0)      qb[(bhx * SEQ + ll) * DH + dd] = val;
                    else if (tt == 1) kb[(bhx * SEQ + ll) * DH + dd] = val;
                    else              vtb[(bhx * DH + dd) * SEQ + ll] = val;  // transposed
                }
            }
        }
    } else {
#pragma unroll
        for (int mt = 0; mt < 4; mt++)
#pragma unroll
            for (int nt = 0; nt < 4; nt++)
#pragma unroll
                for (int r = 0; r < 4; r++) {
                    int row = m0 + wm + mt * 16 + g * 4 + r;
                    int col = n0 + wn + nt * 16 + c16;
                    outp[(size_t)row * N + col] = acc[mt][nt][r] + b_proj[col];
                }
    }
}

// ---------------- fused cosine-sim flash attention (register-only, no LDS) ----------------
// grid: 1024 blocks, gid = h*64 + qt ; block: 4 waves, wave w = batch w, 32 Q-rows.
// K/V are L3-resident (32 MB total) -> load MFMA fragments DIRECTLY from global
// (no LDS, no barriers, no manual waitcnt: compiler emits counted vmcnt for reg loads).
// K-frags + bias double-buffered one full iteration ahead (named regs, x2 unroll);
// V issued at iter top, consumed after S+softmax.
// Swapped QK^T with 32x32x16 (m74/m101 C/D layout); static-max softmax (logits bounded);
// P repack via cvt_pk + permlane32_swap (m214-v22 verified recipe).
struct KT { bf16x8 f[4]; };
struct VT { bf16x8 f[4]; };
struct BT { float4 b[4]; };

__global__ __launch_bounds__(256) void attn_kernel(
    const uint16_t* __restrict__ qb, const uint16_t* __restrict__ kb,
    const uint16_t* __restrict__ vtb, const float* __restrict__ bias,
    uint16_t* __restrict__ ob)
{
    const int t = threadIdx.x;
    const int w = t >> 6, lane = t & 63;       // wave index == batch index
    const int c32 = lane & 31, hi = lane >> 5;

    const int h = blockIdx.x >> 6;
    const int qt = blockIdx.x & 63;
    const int q0 = qt * 32;
    const size_t bh = (size_t)w * NH + h;

    // per-lane base pointers
    const uint16_t* kbase = kb + (bh * SEQ + c32) * DH + hi * 8;      // + k0*DH + s*16
    const uint16_t* vb0   = vtb + (bh * DH + c32) * SEQ + hi * 8;     // + db*32*SEQ + k0 + c*16
    const uint16_t* vb1   = vb0 + (size_t)32 * SEQ;
    const float* bias_base = bias + ((size_t)h * SEQ + q0 + c32) * SEQ;  // + k0 + tt*8 + hi*4

    auto loadK = [&](int k0) {
        KT k;
#pragma unroll
        for (int s = 0; s < 4; s++)
            k.f[s] = *(const bf16x8*)(kbase + (size_t)k0 * DH + s * 16);
        return k;
    };
    auto loadV = [&](int k0) {
        VT v;
#pragma unroll
        for (int c = 0; c < 2; c++) {
            v.f[c]     = *(const bf16x8*)(vb0 + k0 + c * 16);   // db=0
            v.f[2 + c] = *(const bf16x8*)(vb1 + k0 + c * 16);   // db=1
        }
        return v;
    };
    auto loadB = [&](int k0) {
        BT b;
#pragma unroll
        for (int tt = 0; tt < 4; tt++)
            b.b[tt] = *(const float4*)(bias_base + k0 + tt * 8 + hi * 4);
        return b;
    };

    // Q fragments (q pre-scaled by scale_h*log2e/||q||)
    bf16x8 qf[4];
    const uint16_t* qp = qb + (bh * SEQ + q0 + c32) * DH;
#pragma unroll
    for (int s = 0; s < 4; s++)
        qf[s] = *(const bf16x8*)(qp + s * 16 + hi * 8);

    f32x16 accO0, accO1;
#pragma unroll
    for (int i = 0; i < 16; i++) { accO0[i] = 0.f; accO1[i] = 0.f; }
    float lrun = 0.f;

    auto computeTile = [&](const KT& kf, const BT& bt, const VT& vf) {
        // S^T = K Q^T : reg r -> k_local = (r&3) + 8*(r>>2) + 4*hi ; q-row = c32
        f32x16 S;
#pragma unroll
        for (int i = 0; i < 16; i++) S[i] = 0.f;
#pragma unroll
        for (int s = 0; s < 4; s++)
            S = __builtin_amdgcn_mfma_f32_32x32x16_bf16(kf.f[s], qf[s], S, 0, 0, 0);

        // softmax (static max): p = exp2(S + bias*log2e); bias comp: tt = r>>2, j = r&3
        float p[16];
        float lp = 0.f;
#pragma unroll
        for (int tt = 0; tt < 4; tt++) {
            p[tt * 4 + 0] = exp2_fast(fmaf(bt.b[tt].x, LOG2E, S[tt * 4 + 0]));
            p[tt * 4 + 1] = exp2_fast(fmaf(bt.b[tt].y, LOG2E, S[tt * 4 + 1]));
            p[tt * 4 + 2] = exp2_fast(fmaf(bt.b[tt].z, LOG2E, S[tt * 4 + 2]));
            p[tt * 4 + 3] = exp2_fast(fmaf(bt.b[tt].w, LOG2E, S[tt * 4 + 3]));
            lp += (p[tt * 4 + 0] + p[tt * 4 + 1]) + (p[tt * 4 + 2] + p[tt * 4 + 3]);
        }
        lrun += lp;

        // m214 repack -> PV A-fragments
        bf16x8 pa[2];
#pragma unroll
        for (int cp = 0; cp < 2; cp++) {
            uint32_t X0 = cvt_pk_bf16(p[8 * cp + 0], p[8 * cp + 1]);
            uint32_t X1 = cvt_pk_bf16(p[8 * cp + 2], p[8 * cp + 3]);
            uint32_t Y0 = cvt_pk_bf16(p[8 * cp + 4], p[8 * cp + 5]);
            uint32_t Y1 = cvt_pk_bf16(p[8 * cp + 6], p[8 * cp + 7]);
            p32swap(X0, Y0);
            p32swap(X1, Y1);
            union { uint32_t u[4]; bf16x8 v; } pu;
            pu.u[0] = X0; pu.u[1] = X1; pu.u[2] = Y0; pu.u[3] = Y1;
            pa[cp] = pu.v;
        }

        // O += P V
#pragma unroll
        for (int c = 0; c < 2; c++) {
            accO0 = __builtin_amdgcn_mfma_f32_32x32x16_bf16(pa[c], vf.f[c],     accO0, 0, 0, 0);
            accO1 = __builtin_amdgcn_mfma_f32_32x32x16_bf16(pa[c], vf.f[2 + c], accO1, 0, 0, 0);
        }
    };

    // software pipeline: K/bias prefetched one full tile ahead (A/B register rename),
    // V issued at iter top (covered by S-MFMA + softmax). Wrap-clamped tail loads.
    KT kA = loadK(0);
    BT bA = loadB(0);
    for (int it = 0; it < 64; it += 2) {
        VT v0 = loadV(it * 32);
        KT kB = loadK(((it + 1) & 63) * 32);
        BT bB = loadB(((it + 1) & 63) * 32);
        computeTile(kA, bA, v0);

        VT v1 = loadV((it + 1) * 32);
        kA = loadK(((it + 2) & 63) * 32);
        bA = loadB(((it + 2) & 63) * 32);
        computeTile(kB, bB, v1);
    }

    // finalize: row-sum reduce + redistribute, O /= l, write bf16 [B, L, H*D]
    float s = lrun + __shfl_xor(lrun, 32, 64);
    float inv = 1.0f / s;                     // valid for q-row = c32 on all lanes
    float linv[16];
#pragma unroll
    for (int r = 0; r < 16; r++)
        linv[r] = __shfl(inv, (r & 3) + 8 * (r >> 2) + 4 * hi, 64);
#pragma unroll
    for (int r = 0; r < 16; r++) {
        int rowq = (r & 3) + 8 * (r >> 2) + 4 * hi;
        size_t rowbase = ((size_t)w * SEQ + q0 + rowq) * CMOD + h * DH;
        ob[rowbase + c32]      = f2bf(accO0[r] * linv[r]);
        ob[rowbase + 32 + c32] = f2bf(accO1[r] * linv[r]);
    }
}

// ---------------- launch ----------------
extern "C" void kernel_launch(void* const* d_in, const int* in_sizes, int n_in,
                              void* d_out, int out_size, void* d_ws, size_t ws_size,
                              hipStream_t stream) {
    const float* x             = (const float*)d_in[0];
    const float* attn_bias     = (const float*)d_in[1];
    const float* W_qkv         = (const float*)d_in[2];
    const float* q_bias        = (const float*)d_in[3];
    const float* v_bias        = (const float*)d_in[4];
    const float* scale_mul_log = (const float*)d_in[5];
    const float* W_proj        = (const float*)d_in[6];
    const float* b_proj        = (const float*)d_in[7];
    float* out = (float*)d_out;

    uint8_t* ws = (uint8_t*)d_ws;
    size_t off = 0;
    auto alloc = [&](size_t bytes) { uint8_t* p = ws + off; off += (bytes + 255) & ~(size_t)255; return p; };
    uint16_t* xb     = (uint16_t*)alloc((size_t)8192 * 1024 * 2);
    uint16_t* wqkvb  = (uint16_t*)alloc((size_t)3072 * 1024 * 2);
    uint16_t* wprojb = (uint16_t*)alloc((size_t)1024 * 1024 * 2);
    uint16_t* qb     = (uint16_t*)alloc((size_t)BATCH * NH * SEQ * DH * 2);
    uint16_t* kb     = (uint16_t*)alloc((size_t)BATCH * NH * SEQ * DH * 2);
    uint16_t* vtb    = (uint16_t*)alloc((size_t)BATCH * NH * SEQ * DH * 2);
    uint16_t* ob     = (uint16_t*)alloc((size_t)BATCH * SEQ * CMOD * 2);
    (void)ws_size;

    cvt_kernel<<<8192, 256, 0, stream>>>(x, xb, 8388608);
    cvt_kernel<<<3072, 256, 0, stream>>>(W_qkv, wqkvb, 3145728);
    cvt_kernel<<<1024, 256, 0, stream>>>(W_proj, wprojb, 1048576);

    dim3 g1(64, 24);
    gemm_bt_kernel<<<g1, 256, 0, stream>>>(xb, wqkvb, 8192, 3072, 1024, 0,
                                           qb, kb, vtb, q_bias, v_bias, scale_mul_log,
                                           nullptr, nullptr);

    attn_kernel<<<1024, 256, 0, stream>>>(qb, kb, vtb, attn_bias, ob);

    dim3 g3(64, 8);
    gemm_bt_kernel<<<g3, 256, 0, stream>>>(ob, wprojb, 8192, 1024, 1024, 1,
                                           nullptr, nullptr, nullptr, nullptr, nullptr, nullptr,
                                           out, b_proj);
}

// Round 7
// 445.115 us; speedup vs baseline: 1.2178x; 1.2178x over previous
//
#include <hip/hip_runtime.h>
#include <cstdint>
#include <cstddef>

// Problem constants
#define BATCH 4
#define SEQ   2048
#define CMOD  1024
#define NH    16
#define DH    64
#define LOG100 4.6051701859880914f
#define LOG2E  1.4426950408889634f

typedef __attribute__((ext_vector_type(8))) short bf16x8;
typedef __attribute__((ext_vector_type(4))) float f32x4;
typedef __attribute__((ext_vector_type(16))) float f32x16;

__device__ __forceinline__ float bf2f(uint16_t u) {
    union { uint32_t i; float f; } x; x.i = ((uint32_t)u) << 16; return x.f;
}
__device__ __forceinline__ uint16_t f2bf(float f) {
    union { float f; uint32_t i; } x; x.f = f;
    uint32_t u = x.i;
    return (uint16_t)((u + 0x7FFFu + ((u >> 16) & 1u)) >> 16);  // RNE
}
__device__ __forceinline__ float exp2_fast(float x) {
    float r; asm("v_exp_f32 %0, %1" : "=v"(r) : "v"(x)); return r;
}
__device__ __forceinline__ uint32_t cvt_pk_bf16(float lo, float hi) {
    uint32_t r;
    asm("v_cvt_pk_bf16_f32 %0, %1, %2" : "=v"(r) : "v"(lo), "v"(hi));
    return r;
}
__device__ __forceinline__ void p32swap(uint32_t& x, uint32_t& y) {
#if __has_builtin(__builtin_amdgcn_permlane32_swap)
    auto r = __builtin_amdgcn_permlane32_swap(x, y, false, false);
    x = r[0]; y = r[1];
#else
    asm volatile("v_permlane32_swap_b32 %0, %1\n\ts_nop 1" : "+v"(x), "+v"(y));
#endif
}

__device__ __forceinline__ void gload_lds16(const void* g, void* l) {
    __builtin_amdgcn_global_load_lds(
        (const __attribute__((address_space(1))) uint32_t*)g,
        (__attribute__((address_space(3))) uint32_t*)l,
        16, 0, 0);
}

// ---------------- fp32 -> bf16 convert ----------------
__global__ __launch_bounds__(256) void cvt_kernel(const float* __restrict__ in,
                                                  uint16_t* __restrict__ out, int n) {
    int i = (blockIdx.x * 256 + threadIdx.x) * 4;
    if (i >= n) return;
    float4 f = *(const float4*)(in + i);
    ushort4 o;
    o.x = f2bf(f.x); o.y = f2bf(f.y); o.z = f2bf(f.z); o.w = f2bf(f.w);
    *(ushort4*)(out + i) = o;
}

// ---------------- bf16 GEMM, B-transposed input (m97 structure) ----------------
// C[M,N] = A[M,K] * B[N,K]^T ; 128x128 tile, BK=32, 4 waves, 4x4 16x16x32 frags/wave
// mode 0: QKV epilogue -> q normalized*scale_h*log2e (bf16 [B,H,L,D]),
//         k normalized (bf16 [B,H,L,D]), v+bias pre-transposed (bf16 [B,H,D,L])
// mode 1: proj epilogue -> fp32 out + b_proj
__global__ __launch_bounds__(256) void gemm_bt_kernel(
    const uint16_t* __restrict__ A, const uint16_t* __restrict__ B,
    int M, int N, int K, int mode,
    uint16_t* __restrict__ qb, uint16_t* __restrict__ kb, uint16_t* __restrict__ vtb,
    const float* __restrict__ q_bias, const float* __restrict__ v_bias,
    const float* __restrict__ scale_mul_log,
    float* __restrict__ outp, const float* __restrict__ b_proj)
{
    __shared__ __align__(16) uint16_t As[128 * 32];
    __shared__ __align__(16) uint16_t Bs[128 * 32];
    const int t = threadIdx.x;
    const int wave = t >> 6, lane = t & 63;
    const int g = lane >> 4, c16 = lane & 15;
    const int m0 = blockIdx.x * 128, n0 = blockIdx.y * 128;
    const int wm = (wave >> 1) * 64, wn = (wave & 1) * 64;

    f32x4 acc[4][4];
#pragma unroll
    for (int mt = 0; mt < 4; mt++)
#pragma unroll
        for (int nt = 0; nt < 4; nt++) acc[mt][nt] = (f32x4){0.f, 0.f, 0.f, 0.f};

    for (int k0 = 0; k0 < K; k0 += 32) {
        __syncthreads();
#pragma unroll
        for (int i = 0; i < 2; i++) {
            int cc = i * 256 + t;           // 512 chunks of 8 elems
            int row = cc >> 2, col = (cc & 3) * 8;
            gload_lds16(A + (size_t)(m0 + row) * K + k0 + col, &As[cc * 8]);
            gload_lds16(B + (size_t)(n0 + row) * K + k0 + col, &Bs[cc * 8]);
        }
        __syncthreads();
        bf16x8 af[4], bfv[4];
#pragma unroll
        for (int mt = 0; mt < 4; mt++)
            af[mt] = *(const bf16x8*)&As[(wm + mt * 16 + c16) * 32 + g * 8];
#pragma unroll
        for (int nt = 0; nt < 4; nt++)
            bfv[nt] = *(const bf16x8*)&Bs[(wn + nt * 16 + c16) * 32 + g * 8];
#pragma unroll
        for (int mt = 0; mt < 4; mt++)
#pragma unroll
            for (int nt = 0; nt < 4; nt++)
                acc[mt][nt] = __builtin_amdgcn_mfma_f32_16x16x32_bf16(af[mt], bfv[nt], acc[mt][nt], 0, 0, 0);
    }

    if (mode == 0) {
        const int colbase = n0 + wn;          // multiple of 64 -> single (tt, head) per wave
        const int tt = colbase >> 10;
        const int cc0 = colbase & 1023;
        const int hh = cc0 >> 6;
        float qmul = 1.0f;
        if (tt == 0) qmul = __expf(fminf(scale_mul_log[hh], LOG100)) * LOG2E;
#pragma unroll
        for (int mt = 0; mt < 4; mt++) {
            float vals[4][4];
            float n2[4] = {0.f, 0.f, 0.f, 0.f};
#pragma unroll
            for (int nt = 0; nt < 4; nt++) {
                const int ci = cc0 + nt * 16 + c16;   // 0..1023 within qkv third
                float badd = 0.f;
                if (tt == 0) badd = q_bias[ci];
                else if (tt == 2) badd = v_bias[ci];
#pragma unroll
                for (int r = 0; r < 4; r++) {
                    float v = acc[mt][nt][r] + badd;
                    vals[nt][r] = v;
                    n2[r] += v * v;
                }
            }
            float rs[4];
            if (tt < 2) {   // L2-normalize q (with scale*log2e) and k over the 64-wide head dim
#pragma unroll
                for (int r = 0; r < 4; r++) {
                    float s = n2[r];
                    s += __shfl_xor(s, 1, 64);
                    s += __shfl_xor(s, 2, 64);
                    s += __shfl_xor(s, 4, 64);
                    s += __shfl_xor(s, 8, 64);
                    rs[r] = qmul / fmaxf(sqrtf(s), 1e-12f);
                }
            } else {
#pragma unroll
                for (int r = 0; r < 4; r++) rs[r] = 1.0f;
            }
#pragma unroll
            for (int nt = 0; nt < 4; nt++) {
                const int dd = (cc0 + nt * 16 + c16) & 63;
#pragma unroll
                for (int r = 0; r < 4; r++) {
                    const int row = m0 + wm + mt * 16 + g * 4 + r;   // b*2048 + l
                    const int bb = row >> 11, ll = row & 2047;
                    const size_t bhx = (size_t)bb * NH + hh;
                    const uint16_t val = f2bf(vals[nt][r] * rs[r]);
                    if (tt == 0)      qb[(bhx * SEQ + ll) * DH + dd] = val;
                    else if (tt == 1) kb[(bhx * SEQ + ll) * DH + dd] = val;
                    else              vtb[(bhx * DH + dd) * SEQ + ll] = val;  // transposed
                }
            }
        }
    } else {
#pragma unroll
        for (int mt = 0; mt < 4; mt++)
#pragma unroll
            for (int nt = 0; nt < 4; nt++)
#pragma unroll
                for (int r = 0; r < 4; r++) {
                    int row = m0 + wm + mt * 16 + g * 4 + r;
                    int col = n0 + wn + nt * 16 + c16;
                    outp[(size_t)row * N + col] = acc[mt][nt][r] + b_proj[col];
                }
    }
}

// ---------------- fused cosine-sim flash attention (2-phase dbuf, 32x32 core) ----------------
// grid: 512 blocks, gid = h*32 + qt ; block: 4 waves, wave w = batch w, 64 Q-rows (2 qg).
// KVBLK=32, double-buffered fragment-linear LDS ([buf][batch][slot][lane*16B], staged
// via coalesced gload_lds -> conflict-free ds_read_b128, proven R5).
// T3 minimum 2-phase (m230/m248-proven): bias(t) -> stage(t+1) -> compute(t) -> barrier.
// Bias issued FIRST so its wait is counted vmcnt, not a drain; barrier puts the
// vmcnt(0) drain at iter END (stage had the whole compute phase in flight).
// Core: swapped mfma(K,Q) 32x32x16 (m74/m101 layout), static-max softmax,
// cvt_pk + permlane32_swap repack (m214-v22 recipe). Numerics identical to R4/R5/R6.
__global__ __launch_bounds__(256, 2) void attn_kernel(
    const uint16_t* __restrict__ qb, const uint16_t* __restrict__ kb,
    const uint16_t* __restrict__ vtb, const float* __restrict__ bias,
    uint16_t* __restrict__ ob)
{
    __shared__ __align__(16) uint16_t KsL[2][4][4][512];  // [buf][batch][slot][lane*8] 16KB
    __shared__ __align__(16) uint16_t VsL[2][4][4][512];  // 16KB ; total 64KB

    const int t = threadIdx.x;
    const int w = t >> 6, lane = t & 63;       // wave index == batch index
    const int c32 = lane & 31, hi = lane >> 5;

    const int h = blockIdx.x >> 5;
    const int qt = blockIdx.x & 31;
    const int q0 = qt * 64;
    const size_t bh = (size_t)w * NH + h;

    const uint16_t* kbase = kb + (bh * SEQ + c32) * DH + hi * 8;
    const float* bias_base = bias + ((size_t)h * SEQ + q0 + c32) * SEQ;

    // stage KVBLK=32 for this wave's batch (fragment-linear slots, coalesced DMA)
    auto stage = [&](int k0, int buf) {
#pragma unroll
        for (int s = 0; s < 4; s++)
            gload_lds16(kbase + (size_t)k0 * DH + s * 16, &KsL[buf][w][s][lane * 8]);
#pragma unroll
        for (int j = 0; j < 4; j++)
            gload_lds16(vtb + (bh * DH + (j >> 1) * 32 + c32) * SEQ + k0 + (j & 1) * 16 + hi * 8,
                        &VsL[buf][w][j][lane * 8]);
    };

    // Q fragments: 2 q-groups x 4 d-subtiles (q pre-scaled by scale_h*log2e/||q||)
    bf16x8 qf[2][4];
#pragma unroll
    for (int qg = 0; qg < 2; qg++) {
        const uint16_t* qp = qb + (bh * SEQ + q0 + qg * 32 + c32) * DH;
#pragma unroll
        for (int s = 0; s < 4; s++)
            qf[qg][s] = *(const bf16x8*)(qp + s * 16 + hi * 8);
    }

    f32x16 accO[2][2];
#pragma unroll
    for (int qg = 0; qg < 2; qg++)
#pragma unroll
        for (int db = 0; db < 2; db++)
#pragma unroll
            for (int i = 0; i < 16; i++) accO[qg][db][i] = 0.f;
    float lrun[2] = {0.f, 0.f};

    stage(0, 0);
    __syncthreads();

    for (int it = 0; it < 64; ++it) {
        const int k0 = it * 32;
        const int cur = it & 1;

        // bias loads FIRST: their wait is a counted vmcnt (stage ops issued after)
        float4 bb[2][4];
#pragma unroll
        for (int qg = 0; qg < 2; qg++)
#pragma unroll
            for (int tt = 0; tt < 4; tt++)
                bb[qg][tt] = *(const float4*)(bias_base + (size_t)(qg * 32) * SEQ + k0 + tt * 8 + hi * 4);

        if (it + 1 < 64) stage(k0 + 32, cur ^ 1);

        // S^T = K Q^T : reg r -> k_local = (r&3) + 8*(r>>2) + 4*hi ; q-row = c32
        f32x16 S[2];
#pragma unroll
        for (int qg = 0; qg < 2; qg++)
#pragma unroll
            for (int i = 0; i < 16; i++) S[qg][i] = 0.f;
#pragma unroll
        for (int s = 0; s < 4; s++) {
            bf16x8 kf = *(const bf16x8*)&KsL[cur][w][s][lane * 8];
            S[0] = __builtin_amdgcn_mfma_f32_32x32x16_bf16(kf, qf[0][s], S[0], 0, 0, 0);
            S[1] = __builtin_amdgcn_mfma_f32_32x32x16_bf16(kf, qf[1][s], S[1], 0, 0, 0);
        }

        // softmax (static max: logits bounded by scale<=4 + |bias|) + m214 repack
        bf16x8 pa[2][2];
#pragma unroll
        for (int qg = 0; qg < 2; qg++) {
            float p[16];
            float lp = 0.f;
#pragma unroll
            for (int tt = 0; tt < 4; tt++) {
                p[tt * 4 + 0] = exp2_fast(fmaf(bb[qg][tt].x, LOG2E, S[qg][tt * 4 + 0]));
                p[tt * 4 + 1] = exp2_fast(fmaf(bb[qg][tt].y, LOG2E, S[qg][tt * 4 + 1]));
                p[tt * 4 + 2] = exp2_fast(fmaf(bb[qg][tt].z, LOG2E, S[qg][tt * 4 + 2]));
                p[tt * 4 + 3] = exp2_fast(fmaf(bb[qg][tt].w, LOG2E, S[qg][tt * 4 + 3]));
                lp += (p[tt * 4 + 0] + p[tt * 4 + 1]) + (p[tt * 4 + 2] + p[tt * 4 + 3]);
            }
            lrun[qg] += lp;
#pragma unroll
            for (int cp = 0; cp < 2; cp++) {
                uint32_t X0 = cvt_pk_bf16(p[8 * cp + 0], p[8 * cp + 1]);
                uint32_t X1 = cvt_pk_bf16(p[8 * cp + 2], p[8 * cp + 3]);
                uint32_t Y0 = cvt_pk_bf16(p[8 * cp + 4], p[8 * cp + 5]);
                uint32_t Y1 = cvt_pk_bf16(p[8 * cp + 6], p[8 * cp + 7]);
                p32swap(X0, Y0);
                p32swap(X1, Y1);
                union { uint32_t u[4]; bf16x8 v; } pu;
                pu.u[0] = X0; pu.u[1] = X1; pu.u[2] = Y0; pu.u[3] = Y1;
                pa[qg][cp] = pu.v;
            }
        }

        // O += P V (V frag slots shared across q-groups)
#pragma unroll
        for (int c = 0; c < 2; c++)
#pragma unroll
            for (int db = 0; db < 2; db++) {
                bf16x8 vf = *(const bf16x8*)&VsL[cur][w][db * 2 + c][lane * 8];
                accO[0][db] = __builtin_amdgcn_mfma_f32_32x32x16_bf16(pa[0][c], vf, accO[0][db], 0, 0, 0);
                accO[1][db] = __builtin_amdgcn_mfma_f32_32x32x16_bf16(pa[1][c], vf, accO[1][db], 0, 0, 0);
            }

        __syncthreads();   // drain lands HERE: stage(t+1) had the whole compute in flight
    }

    // finalize: row-sum reduce + redistribute, O /= l, write bf16 [B, L, H*D]
#pragma unroll
    for (int qg = 0; qg < 2; qg++) {
        float s = lrun[qg] + __shfl_xor(lrun[qg], 32, 64);
        float inv = 1.0f / s;                 // valid for q-row = c32 on all lanes
        float linv[16];
#pragma unroll
        for (int r = 0; r < 16; r++)
            linv[r] = __shfl(inv, (r & 3) + 8 * (r >> 2) + 4 * hi, 64);
#pragma unroll
        for (int r = 0; r < 16; r++) {
            int rowq = (r & 3) + 8 * (r >> 2) + 4 * hi;
            size_t rowbase = ((size_t)w * SEQ + q0 + qg * 32 + rowq) * CMOD + h * DH;
            ob[rowbase + c32]      = f2bf(accO[qg][0][r] * linv[r]);
            ob[rowbase + 32 + c32] = f2bf(accO[qg][1][r] * linv[r]);
        }
    }
}

// ---------------- launch ----------------
extern "C" void kernel_launch(void* const* d_in, const int* in_sizes, int n_in,
                              void* d_out, int out_size, void* d_ws, size_t ws_size,
                              hipStream_t stream) {
    const float* x             = (const float*)d_in[0];
    const float* attn_bias     = (const float*)d_in[1];
    const float* W_qkv         = (const float*)d_in[2];
    const float* q_bias        = (const float*)d_in[3];
    const float* v_bias        = (const float*)d_in[4];
    const float* scale_mul_log = (const float*)d_in[5];
    const float* W_proj        = (const float*)d_in[6];
    const float* b_proj        = (const float*)d_in[7];
    float* out = (float*)d_out;

    uint8_t* ws = (uint8_t*)d_ws;
    size_t off = 0;
    auto alloc = [&](size_t bytes) { uint8_t* p = ws + off; off += (bytes + 255) & ~(size_t)255; return p; };
    uint16_t* xb     = (uint16_t*)alloc((size_t)8192 * 1024 * 2);
    uint16_t* wqkvb  = (uint16_t*)alloc((size_t)3072 * 1024 * 2);
    uint16_t* wprojb = (uint16_t*)alloc((size_t)1024 * 1024 * 2);
    uint16_t* qb     = (uint16_t*)alloc((size_t)BATCH * NH * SEQ * DH * 2);
    uint16_t* kb     = (uint16_t*)alloc((size_t)BATCH * NH * SEQ * DH * 2);
    uint16_t* vtb    = (uint16_t*)alloc((size_t)BATCH * NH * SEQ * DH * 2);
    uint16_t* ob     = (uint16_t*)alloc((size_t)BATCH * SEQ * CMOD * 2);
    (void)ws_size;

    cvt_kernel<<<8192, 256, 0, stream>>>(x, xb, 8388608);
    cvt_kernel<<<3072, 256, 0, stream>>>(W_qkv, wqkvb, 3145728);
    cvt_kernel<<<1024, 256, 0, stream>>>(W_proj, wprojb, 1048576);

    dim3 g1(64, 24);
    gemm_bt_kernel<<<g1, 256, 0, stream>>>(xb, wqkvb, 8192, 3072, 1024, 0,
                                           qb, kb, vtb, q_bias, v_bias, scale_mul_log,
                                           nullptr, nullptr);

    attn_kernel<<<512, 256, 0, stream>>>(qb, kb, vtb, attn_bias, ob);

    dim3 g3(64, 8);
    gemm_bt_kernel<<<g3, 256, 0, stream>>>(ob, wprojb, 8192, 1024, 1024, 1,
                                           nullptr, nullptr, nullptr, nullptr, nullptr, nullptr,
                                           out, b_proj);
}

// Round 8
// 372.041 us; speedup vs baseline: 1.4569x; 1.1964x over previous
//
#include <hip/hip_runtime.h>
#include <cstdint>
#include <cstddef>

// Problem constants
#define BATCH 4
#define SEQ   2048
#define CMOD  1024
#define NH    16
#define DH    64
#define LOG100 4.6051701859880914f
#define LOG2E  1.4426950408889634f

typedef __attribute__((ext_vector_type(8))) short bf16x8;
typedef __attribute__((ext_vector_type(4))) float f32x4;
typedef __attribute__((ext_vector_type(16))) float f32x16;

__device__ __forceinline__ float bf2f(uint16_t u) {
    union { uint32_t i; float f; } x; x.i = ((uint32_t)u) << 16; return x.f;
}
__device__ __forceinline__ uint16_t f2bf(float f) {
    union { float f; uint32_t i; } x; x.f = f;
    uint32_t u = x.i;
    return (uint16_t)((u + 0x7FFFu + ((u >> 16) & 1u)) >> 16);  // RNE
}
__device__ __forceinline__ float exp2_fast(float x) {
    float r; asm("v_exp_f32 %0, %1" : "=v"(r) : "v"(x)); return r;
}
__device__ __forceinline__ uint32_t cvt_pk_bf16(float lo, float hi) {
    uint32_t r;
    asm("v_cvt_pk_bf16_f32 %0, %1, %2" : "=v"(r) : "v"(lo), "v"(hi));
    return r;
}
__device__ __forceinline__ void p32swap(uint32_t& x, uint32_t& y) {
#if __has_builtin(__builtin_amdgcn_permlane32_swap)
    auto r = __builtin_amdgcn_permlane32_swap(x, y, false, false);
    x = r[0]; y = r[1];
#else
    asm volatile("v_permlane32_swap_b32 %0, %1\n\ts_nop 1" : "+v"(x), "+v"(y));
#endif
}

__device__ __forceinline__ void gload_lds16(const void* g, void* l) {
    __builtin_amdgcn_global_load_lds(
        (const __attribute__((address_space(1))) uint32_t*)g,
        (__attribute__((address_space(3))) uint32_t*)l,
        16, 0, 0);
}

// ---------------- fp32 -> bf16 convert ----------------
__global__ __launch_bounds__(256) void cvt_kernel(const float* __restrict__ in,
                                                  uint16_t* __restrict__ out, int n) {
    int i = (blockIdx.x * 256 + threadIdx.x) * 4;
    if (i >= n) return;
    float4 f = *(const float4*)(in + i);
    ushort4 o;
    o.x = f2bf(f.x); o.y = f2bf(f.y); o.z = f2bf(f.z); o.w = f2bf(f.w);
    *(ushort4*)(out + i) = o;
}

// ---------------- bf16 GEMM, B-transposed input (m97 structure) ----------------
// C[M,N] = A[M,K] * B[N,K]^T ; 128x128 tile, BK=32, 4 waves, 4x4 16x16x32 frags/wave
// mode 0: QKV epilogue -> q normalized*scale_h*log2e (bf16 [B,H,L,D]),
//         k normalized (bf16 [B,H,L,D]), v+bias pre-transposed (bf16 [B,H,D,L])
// mode 1: proj epilogue -> fp32 out + b_proj
__global__ __launch_bounds__(256) void gemm_bt_kernel(
    const uint16_t* __restrict__ A, const uint16_t* __restrict__ B,
    int M, int N, int K, int mode,
    uint16_t* __restrict__ qb, uint16_t* __restrict__ kb, uint16_t* __restrict__ vtb,
    const float* __restrict__ q_bias, const float* __restrict__ v_bias,
    const float* __restrict__ scale_mul_log,
    float* __restrict__ outp, const float* __restrict__ b_proj)
{
    __shared__ __align__(16) uint16_t As[128 * 32];
    __shared__ __align__(16) uint16_t Bs[128 * 32];
    const int t = threadIdx.x;
    const int wave = t >> 6, lane = t & 63;
    const int g = lane >> 4, c16 = lane & 15;
    const int m0 = blockIdx.x * 128, n0 = blockIdx.y * 128;
    const int wm = (wave >> 1) * 64, wn = (wave & 1) * 64;

    f32x4 acc[4][4];
#pragma unroll
    for (int mt = 0; mt < 4; mt++)
#pragma unroll
        for (int nt = 0; nt < 4; nt++) acc[mt][nt] = (f32x4){0.f, 0.f, 0.f, 0.f};

    for (int k0 = 0; k0 < K; k0 += 32) {
        __syncthreads();
#pragma unroll
        for (int i = 0; i < 2; i++) {
            int cc = i * 256 + t;           // 512 chunks of 8 elems
            int row = cc >> 2, col = (cc & 3) * 8;
            gload_lds16(A + (size_t)(m0 + row) * K + k0 + col, &As[cc * 8]);
            gload_lds16(B + (size_t)(n0 + row) * K + k0 + col, &Bs[cc * 8]);
        }
        __syncthreads();
        bf16x8 af[4], bfv[4];
#pragma unroll
        for (int mt = 0; mt < 4; mt++)
            af[mt] = *(const bf16x8*)&As[(wm + mt * 16 + c16) * 32 + g * 8];
#pragma unroll
        for (int nt = 0; nt < 4; nt++)
            bfv[nt] = *(const bf16x8*)&Bs[(wn + nt * 16 + c16) * 32 + g * 8];
#pragma unroll
        for (int mt = 0; mt < 4; mt++)
#pragma unroll
            for (int nt = 0; nt < 4; nt++)
                acc[mt][nt] = __builtin_amdgcn_mfma_f32_16x16x32_bf16(af[mt], bfv[nt], acc[mt][nt], 0, 0, 0);
    }

    if (mode == 0) {
        const int colbase = n0 + wn;          // multiple of 64 -> single (tt, head) per wave
        const int tt = colbase >> 10;
        const int cc0 = colbase & 1023;
        const int hh = cc0 >> 6;
        float qmul = 1.0f;
        if (tt == 0) qmul = __expf(fminf(scale_mul_log[hh], LOG100)) * LOG2E;
#pragma unroll
        for (int mt = 0; mt < 4; mt++) {
            float vals[4][4];
            float n2[4] = {0.f, 0.f, 0.f, 0.f};
#pragma unroll
            for (int nt = 0; nt < 4; nt++) {
                const int ci = cc0 + nt * 16 + c16;   // 0..1023 within qkv third
                float badd = 0.f;
                if (tt == 0) badd = q_bias[ci];
                else if (tt == 2) badd = v_bias[ci];
#pragma unroll
                for (int r = 0; r < 4; r++) {
                    float v = acc[mt][nt][r] + badd;
                    vals[nt][r] = v;
                    n2[r] += v * v;
                }
            }
            float rs[4];
            if (tt < 2) {   // L2-normalize q (with scale*log2e) and k over the 64-wide head dim
#pragma unroll
                for (int r = 0; r < 4; r++) {
                    float s = n2[r];
                    s += __shfl_xor(s, 1, 64);
                    s += __shfl_xor(s, 2, 64);
                    s += __shfl_xor(s, 4, 64);
                    s += __shfl_xor(s, 8, 64);
                    rs[r] = qmul / fmaxf(sqrtf(s), 1e-12f);
                }
            } else {
#pragma unroll
                for (int r = 0; r < 4; r++) rs[r] = 1.0f;
            }
#pragma unroll
            for (int nt = 0; nt < 4; nt++) {
                const int dd = (cc0 + nt * 16 + c16) & 63;
#pragma unroll
                for (int r = 0; r < 4; r++) {
                    const int row = m0 + wm + mt * 16 + g * 4 + r;   // b*2048 + l
                    const int bb = row >> 11, ll = row & 2047;
                    const size_t bhx = (size_t)bb * NH + hh;
                    const uint16_t val = f2bf(vals[nt][r] * rs[r]);
                    if (tt == 0)      qb[(bhx * SEQ + ll) * DH + dd] = val;
                    else if (tt == 1) kb[(bhx * SEQ + ll) * DH + dd] = val;
                    else              vtb[(bhx * DH + dd) * SEQ + ll] = val;  // transposed
                }
            }
        }
    } else {
#pragma unroll
        for (int mt = 0; mt < 4; mt++)
#pragma unroll
            for (int nt = 0; nt < 4; nt++)
#pragma unroll
                for (int r = 0; r < 4; r++) {
                    int row = m0 + wm + mt * 16 + g * 4 + r;
                    int col = n0 + wn + nt * 16 + c16;
                    outp[(size_t)row * N + col] = acc[mt][nt][r] + b_proj[col];
                }
    }
}

// ---------------- fused cosine-sim flash attention (KVBLK=128, bias 512B bursts) ----------------
// grid: 1024 blocks, gid = ((qt*16 + h)*4 + b), b innermost -> the 4 b-siblings that
// share a bias tile are co-resident (bias read once from HBM, 3x L2/L3 hits).
// block: 4 waves, ALL on batch b; wave w owns q-rows [qt*128 + w*32, +32).
// Per iter: stage K[128][64] + V^T[64][128] (contiguous global reads, within-row
// XOR chunk-swizzle -> 4-way-max LDS frag reads); bias = 16 float4/lane in ONE burst
// (512B contiguous per q-row per iter = the DRAM-efficiency lever).
// Core: swapped mfma(K,Q) 32x32x16 (m74/m101 layout), static-max softmax,
// cvt_pk + permlane32_swap repack (m214-v22). Formulas identical to R7 (passed).
__global__ __launch_bounds__(256, 2) void attn_kernel(
    const uint16_t* __restrict__ qb, const uint16_t* __restrict__ kb,
    const uint16_t* __restrict__ vtb, const float* __restrict__ bias,
    uint16_t* __restrict__ ob)
{
    __shared__ __align__(16) uint16_t Ks[128 * 64];   // 16 KB, row r: chunk j at j^(r&7)
    __shared__ __align__(16) uint16_t Vs[64 * 128];   // 16 KB, row r: chunk j at j^((r&7)<<1)

    const int t = threadIdx.x;
    const int w = t >> 6, lane = t & 63;
    const int c32 = lane & 31, hi = lane >> 5;

    const int gid = blockIdx.x;
    const int b = gid & 3;
    const int h = (gid >> 2) & 15;
    const int qt = gid >> 6;                 // 0..15
    const size_t bh = (size_t)b * NH + h;
    const int q0w = qt * 128 + w * 32;       // this wave's q-base

    // Q fragments (q pre-scaled by scale_h*log2e/||q||)
    bf16x8 qf[4];
    {
        const uint16_t* qp = qb + (bh * SEQ + q0w + c32) * DH;
#pragma unroll
        for (int s = 0; s < 4; s++)
            qf[s] = *(const bf16x8*)(qp + s * 16 + hi * 8);
    }

    f32x16 accO[2];
#pragma unroll
    for (int db = 0; db < 2; db++)
#pragma unroll
        for (int i = 0; i < 16; i++) accO[db][i] = 0.f;
    float lrun = 0.f;

    const float* bias_base = bias + ((size_t)h * SEQ + q0w + c32) * SEQ + hi * 4;

    for (int it = 0; it < 16; ++it) {
        const int k0 = it * 128;
        __syncthreads();   // previous tile fully consumed

        // bias: one 512B-per-row burst (16 float4/lane; hi-lanes interleave to cover it)
        float4 bb[16];
#pragma unroll
        for (int i = 0; i < 16; i++)
            bb[i] = *(const float4*)(bias_base + k0 + i * 8);

        // stage K tile [128 rows][64 d]: 1024 chunks, row-linear global (contiguous 16KB)
#pragma unroll
        for (int i = 0; i < 4; i++) {
            int c = i * 256 + t;
            int row = c >> 3, jc = c & 7, sj = jc ^ (row & 7);
            gload_lds16(kb + (bh * SEQ + k0 + row) * DH + sj * 8, &Ks[c * 8]);
        }
        // stage V^T tile [64 d-rows][128 k]: 1024 chunks (256B contiguous per row)
#pragma unroll
        for (int i = 0; i < 4; i++) {
            int c = i * 256 + t;
            int row = c >> 4, jc = c & 15, sj = jc ^ ((row & 7) << 1);
            gload_lds16(vtb + (bh * DH + row) * SEQ + k0 + sj * 8, &Vs[c * 8]);
        }
        __syncthreads();   // staging (and bias) drained

#pragma unroll
        for (int kb2 = 0; kb2 < 4; kb2++) {
            // S^T = K Q^T : reg r -> k_local = kb2*32 + (r&3)+8*(r>>2)+4*hi ; q-row = c32
            f32x16 S;
#pragma unroll
            for (int i = 0; i < 16; i++) S[i] = 0.f;
#pragma unroll
            for (int s = 0; s < 4; s++) {
                int row = kb2 * 32 + c32;
                int jc = 2 * s + hi;
                bf16x8 kf = *(const bf16x8*)&Ks[(row * 8 + (jc ^ (row & 7))) * 8];
                S = __builtin_amdgcn_mfma_f32_32x32x16_bf16(kf, qf[s], S, 0, 0, 0);
            }

            // softmax (static max: logits bounded by scale<=4 + |bias|)
            float p[16];
            float lp = 0.f;
#pragma unroll
            for (int tt = 0; tt < 4; tt++) {
                float4 b4 = bb[kb2 * 4 + tt];
                p[tt * 4 + 0] = exp2_fast(fmaf(b4.x, LOG2E, S[tt * 4 + 0]));
                p[tt * 4 + 1] = exp2_fast(fmaf(b4.y, LOG2E, S[tt * 4 + 1]));
                p[tt * 4 + 2] = exp2_fast(fmaf(b4.z, LOG2E, S[tt * 4 + 2]));
                p[tt * 4 + 3] = exp2_fast(fmaf(b4.w, LOG2E, S[tt * 4 + 3]));
                lp += (p[tt * 4 + 0] + p[tt * 4 + 1]) + (p[tt * 4 + 2] + p[tt * 4 + 3]);
            }
            lrun += lp;

            // m214 repack -> PV A-fragments for this 32-k block
            bf16x8 pa[2];
#pragma unroll
            for (int cp = 0; cp < 2; cp++) {
                uint32_t X0 = cvt_pk_bf16(p[8 * cp + 0], p[8 * cp + 1]);
                uint32_t X1 = cvt_pk_bf16(p[8 * cp + 2], p[8 * cp + 3]);
                uint32_t Y0 = cvt_pk_bf16(p[8 * cp + 4], p[8 * cp + 5]);
                uint32_t Y1 = cvt_pk_bf16(p[8 * cp + 6], p[8 * cp + 7]);
                p32swap(X0, Y0);
                p32swap(X1, Y1);
                union { uint32_t u[4]; bf16x8 v; } pu;
                pu.u[0] = X0; pu.u[1] = X1; pu.u[2] = Y0; pu.u[3] = Y1;
                pa[cp] = pu.v;
            }

            // O += P V for this 32-k block
#pragma unroll
            for (int c = 0; c < 2; c++)
#pragma unroll
                for (int db = 0; db < 2; db++) {
                    int vrow = db * 32 + c32;
                    int vjc = kb2 * 4 + 2 * c + hi;
                    bf16x8 vf = *(const bf16x8*)&Vs[(vrow * 16 + (vjc ^ ((vrow & 7) << 1))) * 8];
                    accO[db] = __builtin_amdgcn_mfma_f32_32x32x16_bf16(pa[c], vf, accO[db], 0, 0, 0);
                }
        }
    }

    // finalize: row-sum reduce + redistribute, O /= l, write bf16 [B, L, H*D]
    float s = lrun + __shfl_xor(lrun, 32, 64);
    float inv = 1.0f / s;                     // valid for q-row = c32 on all lanes
    float linv[16];
#pragma unroll
    for (int r = 0; r < 16; r++)
        linv[r] = __shfl(inv, (r & 3) + 8 * (r >> 2) + 4 * hi, 64);
#pragma unroll
    for (int r = 0; r < 16; r++) {
        int rowq = (r & 3) + 8 * (r >> 2) + 4 * hi;
        size_t rowbase = ((size_t)b * SEQ + q0w + rowq) * CMOD + h * DH;
        ob[rowbase + c32]      = f2bf(accO[0][r] * linv[r]);
        ob[rowbase + 32 + c32] = f2bf(accO[1][r] * linv[r]);
    }
}

// ---------------- launch ----------------
extern "C" void kernel_launch(void* const* d_in, const int* in_sizes, int n_in,
                              void* d_out, int out_size, void* d_ws, size_t ws_size,
                              hipStream_t stream) {
    const float* x             = (const float*)d_in[0];
    const float* attn_bias     = (const float*)d_in[1];
    const float* W_qkv         = (const float*)d_in[2];
    const float* q_bias        = (const float*)d_in[3];
    const float* v_bias        = (const float*)d_in[4];
    const float* scale_mul_log = (const float*)d_in[5];
    const float* W_proj        = (const float*)d_in[6];
    const float* b_proj        = (const float*)d_in[7];
    float* out = (float*)d_out;

    uint8_t* ws = (uint8_t*)d_ws;
    size_t off = 0;
    auto alloc = [&](size_t bytes) { uint8_t* p = ws + off; off += (bytes + 255) & ~(size_t)255; return p; };
    uint16_t* xb     = (uint16_t*)alloc((size_t)8192 * 1024 * 2);
    uint16_t* wqkvb  = (uint16_t*)alloc((size_t)3072 * 1024 * 2);
    uint16_t* wprojb = (uint16_t*)alloc((size_t)1024 * 1024 * 2);
    uint16_t* qb     = (uint16_t*)alloc((size_t)BATCH * NH * SEQ * DH * 2);
    uint16_t* kb     = (uint16_t*)alloc((size_t)BATCH * NH * SEQ * DH * 2);
    uint16_t* vtb    = (uint16_t*)alloc((size_t)BATCH * NH * SEQ * DH * 2);
    uint16_t* ob     = (uint16_t*)alloc((size_t)BATCH * SEQ * CMOD * 2);
    (void)ws_size;

    cvt_kernel<<<8192, 256, 0, stream>>>(x, xb, 8388608);
    cvt_kernel<<<3072, 256, 0, stream>>>(W_qkv, wqkvb, 3145728);
    cvt_kernel<<<1024, 256, 0, stream>>>(W_proj, wprojb, 1048576);

    dim3 g1(64, 24);
    gemm_bt_kernel<<<g1, 256, 0, stream>>>(xb, wqkvb, 8192, 3072, 1024, 0,
                                           qb, kb, vtb, q_bias, v_bias, scale_mul_log,
                                           nullptr, nullptr);

    attn_kernel<<<1024, 256, 0, stream>>>(qb, kb, vtb, attn_bias, ob);

    dim3 g3(64, 8);
    gemm_bt_kernel<<<g3, 256, 0, stream>>>(ob, wprojb, 8192, 1024, 1024, 1,
                                           nullptr, nullptr, nullptr, nullptr, nullptr, nullptr,
                                           out, b_proj);
}